// Round 1
// baseline (473.846 us; speedup 1.0000x reference)
//
#include <hip/hip_runtime.h>
#include <math.h>

#define N_NODES 50000
#define N_EDGES 800000
#define HD 64

// ---------- helpers ----------
__device__ __forceinline__ float bcast(float v, int lane) {
  // wave-uniform broadcast of lane `lane` (compile-time const after unroll)
  return __int_as_float(__builtin_amdgcn_readlane(__float_as_int(v), lane));
}

// ---------- 1. input projection: h = relu(x @ Wp + bp) ----------
__global__ __launch_bounds__(256) void k_proj(const float* __restrict__ x,
                                              const float* __restrict__ Wp,
                                              const float* __restrict__ bp,
                                              float* __restrict__ h) {
  int idx = blockIdx.x * 256 + threadIdx.x;
  int n = idx >> 6, j = idx & 63;
  if (n >= N_NODES) return;
  float acc = bp[j];
#pragma unroll
  for (int k = 0; k < 10; k++) acc += x[n * 10 + k] * Wp[k * 64 + j];
  h[n * 64 + j] = fmaxf(acc, 0.f);
}

// ---------- 2. CSR build ----------
__global__ __launch_bounds__(256) void k_hist(const int* __restrict__ ei, int* __restrict__ deg) {
  int e = blockIdx.x * 256 + threadIdx.x;
  if (e >= N_EDGES) return;
  atomicAdd(&deg[ei[N_EDGES + e]], 1);
}

__global__ __launch_bounds__(256) void k_scan1(const int* __restrict__ deg,
                                               int* __restrict__ offs,
                                               int* __restrict__ bsums) {
  __shared__ int sm[256];
  int i = blockIdx.x * 256 + threadIdx.x;
  int v = (i < N_NODES) ? deg[i] : 0;
  sm[threadIdx.x] = v;
  __syncthreads();
#pragma unroll
  for (int off = 1; off < 256; off <<= 1) {
    int t = (threadIdx.x >= off) ? sm[threadIdx.x - off] : 0;
    __syncthreads();
    sm[threadIdx.x] += t;
    __syncthreads();
  }
  if (i < N_NODES) offs[i] = sm[threadIdx.x] - v;  // exclusive
  if (threadIdx.x == 255) bsums[blockIdx.x] = sm[255];
}

__global__ __launch_bounds__(256) void k_scan2(int* __restrict__ bsums, int nb) {
  __shared__ int sm[256];
  int t = threadIdx.x;
  int v = (t < nb) ? bsums[t] : 0;
  sm[t] = v;
  __syncthreads();
#pragma unroll
  for (int off = 1; off < 256; off <<= 1) {
    int u = (t >= off) ? sm[t - off] : 0;
    __syncthreads();
    sm[t] += u;
    __syncthreads();
  }
  if (t < nb) bsums[t] = sm[t] - v;  // exclusive
}

__global__ __launch_bounds__(256) void k_scan3(int* __restrict__ offs,
                                               const int* __restrict__ bsums,
                                               int* __restrict__ cursor) {
  int i = blockIdx.x * 256 + threadIdx.x;
  if (i >= N_NODES) return;
  int o = offs[i] + bsums[blockIdx.x];
  offs[i] = o;
  cursor[i] = o;
}

// fill CSR; fuse the 3-layer edge MLP (edge_attr -> sigmoid weight per layer)
__global__ __launch_bounds__(256) void k_fill(const int* __restrict__ ei,
                                              const float* __restrict__ ea,
                                              const float* __restrict__ ew1,
                                              const float* __restrict__ eb1,
                                              const float* __restrict__ ew2,
                                              const float* __restrict__ eb2,
                                              int* __restrict__ cursor,
                                              float4* __restrict__ csr) {
  int e = blockIdx.x * 256 + threadIdx.x;
  if (e >= N_EDGES) return;
  int s = ei[e];
  int d = ei[N_EDGES + e];
  float a0 = ea[e * 3 + 0], a1 = ea[e * 3 + 1], a2 = ea[e * 3 + 2];
  float w[3];
#pragma unroll
  for (int l = 0; l < 3; l++) {
    float z = eb2[l];
#pragma unroll
    for (int t = 0; t < 16; t++) {
      float hd = a0 * ew1[l * 48 + t] + a1 * ew1[l * 48 + 16 + t] +
                 a2 * ew1[l * 48 + 32 + t] + eb1[l * 16 + t];
      z += fmaxf(hd, 0.f) * ew2[l * 16 + t];
    }
    w[l] = 1.f / (1.f + __expf(-z));
  }
  int p = atomicAdd(&cursor[d], 1);
  csr[p] = make_float4(__int_as_float(s), w[0], w[1], w[2]);
}

// ---------- 3. aggregation: wave per node, lane = feature ----------
template <int LI>
__global__ __launch_bounds__(256, 4) void k_agg(const float4* __restrict__ csr,
                                                const int* __restrict__ offs,
                                                const int* __restrict__ deg,
                                                const float* __restrict__ hin,
                                                float* __restrict__ agg) {
  int n = (blockIdx.x * 256 + threadIdx.x) >> 6;
  int j = threadIdx.x & 63;
  if (n >= N_NODES) return;
  int start = offs[n];
  int d = deg[n];
  float acc = 0.f, wsum = 0.f;
  int i = 0;
  for (; i + 4 <= d; i += 4) {
    float4 c0 = csr[start + i + 0];
    float4 c1 = csr[start + i + 1];
    float4 c2 = csr[start + i + 2];
    float4 c3 = csr[start + i + 3];
    float w0 = (LI == 0) ? c0.y : (LI == 1) ? c0.z : c0.w;
    float w1 = (LI == 0) ? c1.y : (LI == 1) ? c1.z : c1.w;
    float w2 = (LI == 0) ? c2.y : (LI == 1) ? c2.z : c2.w;
    float w3 = (LI == 0) ? c3.y : (LI == 1) ? c3.z : c3.w;
    float h0 = hin[__float_as_int(c0.x) * 64 + j];
    float h1 = hin[__float_as_int(c1.x) * 64 + j];
    float h2 = hin[__float_as_int(c2.x) * 64 + j];
    float h3 = hin[__float_as_int(c3.x) * 64 + j];
    acc += h0 * w0 + h1 * w1 + h2 * w2 + h3 * w3;
    wsum += w0 + w1 + w2 + w3;
  }
  for (; i < d; ++i) {
    float4 c = csr[start + i];
    float w = (LI == 0) ? c.y : (LI == 1) ? c.z : c.w;
    acc += hin[__float_as_int(c.x) * 64 + j] * w;
    wsum += w;
  }
  agg[n * 64 + j] = acc / fmaxf(wsum, 1e-12f);
}

// ---------- 4. node MLP + residual + LayerNorm ----------
#define NPW 16  // nodes per wave
__global__ __launch_bounds__(256, 2) void k_mlp(const float* __restrict__ nw,
                                                const float* __restrict__ nb,
                                                const float* __restrict__ g,
                                                const float* __restrict__ b,
                                                const float* __restrict__ hin,
                                                const float* __restrict__ agg,
                                                float* __restrict__ hout) {
  int j = threadIdx.x & 63;
  int gw = (blockIdx.x * 256 + threadIdx.x) >> 6;  // global wave id
  float wreg[128];
#pragma unroll
  for (int k = 0; k < 128; k++) wreg[k] = nw[k * 64 + j];  // lane j = column j
  float nbj = nb[j], gj = g[j], bj = b[j];
  int n0 = gw * NPW;
  for (int n = n0; n < n0 + NPW; ++n) {
    if (n >= N_NODES) break;
    float hv = hin[n * 64 + j];
    float av = agg[n * 64 + j];
    float acc = nbj;
#pragma unroll
    for (int k = 0; k < 64; k++) acc += bcast(hv, k) * wreg[k];
#pragma unroll
    for (int k = 0; k < 64; k++) acc += bcast(av, k) * wreg[64 + k];
    float r = hv + fmaxf(acc, 0.f);
    float s = r;
#pragma unroll
    for (int off = 32; off; off >>= 1) s += __shfl_xor(s, off);
    float mu = s * (1.f / 64.f);
    float dd = r - mu;
    float v2 = dd * dd;
#pragma unroll
    for (int off = 32; off; off >>= 1) v2 += __shfl_xor(v2, off);
    float rs = rsqrtf(v2 * (1.f / 64.f) + 1e-5f);
    hout[n * 64 + j] = dd * rs * gj + bj;
  }
}

// ---------- 5. head: out = relu(h@hw1+hb1)@hw2 + hb2 ----------
__global__ __launch_bounds__(256, 2) void k_head(const float* __restrict__ hw1,
                                                 const float* __restrict__ hb1,
                                                 const float* __restrict__ hw2,
                                                 const float* __restrict__ hb2,
                                                 const float* __restrict__ hin,
                                                 float* __restrict__ out) {
  int j = threadIdx.x & 63;
  int jj = j & 31;
  int gw = (blockIdx.x * 256 + threadIdx.x) >> 6;
  float w1[64];
#pragma unroll
  for (int k = 0; k < 64; k++) w1[k] = hw1[k * 32 + jj];
  float hb1j = hb1[jj];
  float hw2j = hw2[jj];
  float hb2v = hb2[0];
  int n0 = gw * NPW;
  for (int n = n0; n < n0 + NPW; ++n) {
    if (n >= N_NODES) break;
    float hv = hin[n * 64 + j];
    float acc = hb1j;
#pragma unroll
    for (int k = 0; k < 64; k++) acc += bcast(hv, k) * w1[k];
    float z = fmaxf(acc, 0.f) * hw2j;
    if (j >= 32) z = 0.f;  // upper half duplicates lower-half columns
#pragma unroll
    for (int off = 32; off; off >>= 1) z += __shfl_xor(z, off);
    if (j == 0) out[n] = z + hb2v;
  }
}

// ---------- launch ----------
static inline size_t align256(size_t x) { return (x + 255) & ~size_t(255); }

extern "C" void kernel_launch(void* const* d_in, const int* in_sizes, int n_in,
                              void* d_out, int out_size, void* d_ws, size_t ws_size,
                              hipStream_t stream) {
  const float* x   = (const float*)d_in[0];
  const int*   ei  = (const int*)d_in[1];
  const float* ea  = (const float*)d_in[2];
  const float* Wp  = (const float*)d_in[3];
  const float* bp  = (const float*)d_in[4];
  const float* ew1 = (const float*)d_in[5];
  const float* eb1 = (const float*)d_in[6];
  const float* ew2 = (const float*)d_in[7];
  const float* eb2 = (const float*)d_in[8];
  const float* nw  = (const float*)d_in[9];
  const float* nb  = (const float*)d_in[10];
  const float* lng = (const float*)d_in[11];
  const float* lnb = (const float*)d_in[12];
  const float* hw1 = (const float*)d_in[13];
  const float* hb1 = (const float*)d_in[14];
  const float* hw2 = (const float*)d_in[15];
  const float* hb2 = (const float*)d_in[16];
  float* out = (float*)d_out;

  char* ws = (char*)d_ws;
  size_t off = 0;
  float* h0   = (float*)(ws + off); off = align256(off + (size_t)N_NODES * 64 * 4);
  float* h1   = (float*)(ws + off); off = align256(off + (size_t)N_NODES * 64 * 4);
  float* agg  = (float*)(ws + off); off = align256(off + (size_t)N_NODES * 64 * 4);
  float4* csr = (float4*)(ws + off); off = align256(off + (size_t)N_EDGES * 16);
  int* deg    = (int*)(ws + off); off = align256(off + (size_t)N_NODES * 4);
  int* offs   = (int*)(ws + off); off = align256(off + (size_t)N_NODES * 4);
  int* cursor = (int*)(ws + off); off = align256(off + (size_t)N_NODES * 4);
  int* bsums  = (int*)(ws + off); off = align256(off + 1024);

  const int NB_SCAN = (N_NODES + 255) / 256;  // 196

  hipMemsetAsync(deg, 0, (size_t)N_NODES * 4, stream);

  k_proj<<<(N_NODES * 64 + 255) / 256, 256, 0, stream>>>(x, Wp, bp, h0);
  k_hist<<<(N_EDGES + 255) / 256, 256, 0, stream>>>(ei, deg);
  k_scan1<<<NB_SCAN, 256, 0, stream>>>(deg, offs, bsums);
  k_scan2<<<1, 256, 0, stream>>>(bsums, NB_SCAN);
  k_scan3<<<NB_SCAN, 256, 0, stream>>>(offs, bsums, cursor);
  k_fill<<<(N_EDGES + 255) / 256, 256, 0, stream>>>(ei, ea, ew1, eb1, ew2, eb2, cursor, csr);

  const int aggGrid = (N_NODES * 64 + 255) / 256;        // wave per node
  const int mlpGrid = ((N_NODES + NPW - 1) / NPW + 3) / 4;  // 4 waves/block

  // layer 0: h0 -> h1
  k_agg<0><<<aggGrid, 256, 0, stream>>>(csr, offs, deg, h0, agg);
  k_mlp<<<mlpGrid, 256, 0, stream>>>(nw + 0 * 8192, nb + 0 * 64, lng + 0 * 64, lnb + 0 * 64, h0, agg, h1);
  // layer 1: h1 -> h0
  k_agg<1><<<aggGrid, 256, 0, stream>>>(csr, offs, deg, h1, agg);
  k_mlp<<<mlpGrid, 256, 0, stream>>>(nw + 1 * 8192, nb + 1 * 64, lng + 1 * 64, lnb + 1 * 64, h1, agg, h0);
  // layer 2: h0 -> h1
  k_agg<2><<<aggGrid, 256, 0, stream>>>(csr, offs, deg, h0, agg);
  k_mlp<<<mlpGrid, 256, 0, stream>>>(nw + 2 * 8192, nb + 2 * 64, lng + 2 * 64, lnb + 2 * 64, h0, agg, h1);

  k_head<<<mlpGrid, 256, 0, stream>>>(hw1, hb1, hw2, hb2, h1, out);
}